// Round 1
// baseline (788.618 us; speedup 1.0000x reference)
//
#include <hip/hip_runtime.h>
#include <hip/hip_bf16.h>
#include <stdint.h>

#define N_TOKENS 100000
#define N_ARGS   20000
#define N_EDGES  320000
#define IN_DIM   768
#define HEADS    8
#define OUT_DIM  64
#define ZDIM     512   // HEADS*OUT_DIM

typedef unsigned short u16;
typedef unsigned int   u32;
typedef __bf16 bf16x8 __attribute__((ext_vector_type(8)));
typedef float  f32x4  __attribute__((ext_vector_type(4)));

__device__ __forceinline__ u16 f2bf(float f) {
    union { float f; u32 i; } v; v.f = f;
    u32 u = v.i;
    u += 0x7fffu + ((u >> 16) & 1u);   // RNE
    return (u16)(u >> 16);
}
__device__ __forceinline__ float bf2f(u16 u) {
    union { u32 i; float f; } v; v.i = ((u32)u) << 16; return v.f;
}
__device__ __forceinline__ u32 pk(float lo, float hi) {
    __hip_bfloat162 r = __float22bfloat162_rn(float2{lo, hi});
    union { __hip_bfloat162 b; u32 u; } v; v.b = r; return v.u;
}
__device__ __forceinline__ uint4 pack8(const float4 p, const float4 q) {
    uint4 w;
    w.x = pk(p.x, p.y); w.y = pk(p.z, p.w);
    w.z = pk(q.x, q.y); w.w = pk(q.z, q.w);
    return w;
}

// ---------------------------------------------------------------------------
// GEMM: z[M,512] = h[M,768] @ W[512,768]^T  (fp32 in -> bf16 MFMA, bf16 z,
// fp32 s_node fused from the fp32 accumulator)
// 128x128 tile, BK=32, 256 thr = 4 waves, wave = 4x4 16x16x32 MFMAs.
// Round-1 changes:
//  - XCD-aware block swizzle (3128 = 8*391): 4 tileN siblings of a tileM
//    share one XCD's L2 -> A panel fetched ~once from HBM.
//  - XOR slot swizzle on LDS (slot ^= (row>>1)&3): ds_write_b128 goes from
//    4 bank-start positions (16-phase) to 8 (8-phase minimum); reads stay free.
//  - Reg-staged prefetch: kt+1's 8 float4 loads issued after the staging
//    barrier, consumed next iteration -> HBM/L2 latency hidden under MFMAs.
// ---------------------------------------------------------------------------
__global__ __launch_bounds__(256) void gemm_kernel(
    const float* __restrict__ A,      // h [M, K] fp32
    const float* __restrict__ B,      // W [512, K] fp32
    const float* __restrict__ a_attn, // [128] fp32, use first 64
    u16* __restrict__ z,              // [M, 512] bf16
    float* __restrict__ s_node)       // [M, 8] fp32
{
    __shared__ u16 As[128 * 32];
    __shared__ u16 Bs[128 * 32];

    const int tid  = threadIdx.x;
    const int wave = tid >> 6, lane = tid & 63;
    const int quad = lane >> 4, l16 = lane & 15;
    const int wm = wave >> 1, wn = wave & 1;

    // XCD-aware bijective swizzle: grid 3128 = 8 XCDs * 391 blocks.
    // Consecutive lb (same tileM group) land on the same XCD -> L2 A-reuse.
    const int bx = blockIdx.x;
    const int lb = (bx & 7) * 391 + (bx >> 3);
    const int tileN = lb & 3;
    const int tileM = lb >> 2;

    // staging: thread t covers tile row t/2, 16 k-elems starting at (t&1)*16
    const int tr = tid >> 1;
    const int tc = (tid & 1) * 16;
    int ga_row = tileM * 128 + tr; if (ga_row >= N_TOKENS) ga_row = N_TOKENS - 1;
    const float* gA = A + (size_t)ga_row * IN_DIM + tc;
    const float* gB = B + (size_t)(tileN * 128 + tr) * IN_DIM + tc;

    // swizzled LDS write pointers: row = tr, 16B slots s0, s0+1
    const int swr = (tr >> 1) & 3;
    const int s0  = (tid & 1) * 2;
    u16* sA0 = As + tr * 32 + (((s0    ) ^ swr) * 8);
    u16* sA1 = As + tr * 32 + (((s0 + 1) ^ swr) * 8);
    u16* sB0 = Bs + tr * 32 + (((s0    ) ^ swr) * 8);
    u16* sB1 = Bs + tr * 32 + (((s0 + 1) ^ swr) * 8);

    // swizzled LDS read pointers (fragment layout)
    const u16* rA[4];
    const u16* rB[4];
#pragma unroll
    for (int i = 0; i < 4; i++) {
        int r = wm * 64 + i * 16 + l16;
        rA[i] = As + r * 32 + (((quad ^ ((r >> 1) & 3))) * 8);
        r = wn * 64 + i * 16 + l16;
        rB[i] = Bs + r * 32 + (((quad ^ ((r >> 1) & 3))) * 8);
    }

    f32x4 acc[4][4];
    const f32x4 zero4 = {0.f, 0.f, 0.f, 0.f};
#pragma unroll
    for (int i = 0; i < 4; i++)
#pragma unroll
        for (int j = 0; j < 4; j++) acc[i][j] = zero4;

    // prologue: load kt=0 into registers
    float4 a0, a1, a2, a3, b0, b1, b2, b3;
    {
        const float4* pa = reinterpret_cast<const float4*>(gA);
        const float4* pb = reinterpret_cast<const float4*>(gB);
        a0 = pa[0]; a1 = pa[1]; a2 = pa[2]; a3 = pa[3];
        b0 = pb[0]; b1 = pb[1]; b2 = pb[2]; b3 = pb[3];
    }

    for (int kt = 0; kt < IN_DIM / 32; ++kt) {
        __syncthreads();   // previous iteration's LDS reads complete
        reinterpret_cast<uint4*>(sA0)[0] = pack8(a0, a1);
        reinterpret_cast<uint4*>(sA1)[0] = pack8(a2, a3);
        reinterpret_cast<uint4*>(sB0)[0] = pack8(b0, b1);
        reinterpret_cast<uint4*>(sB1)[0] = pack8(b2, b3);
        __syncthreads();   // staging visible to all

        // prefetch kt+1 (clamped; redundant re-load on last iter, valid mem)
        {
            const int kn = (kt < IN_DIM / 32 - 1) ? kt + 1 : kt;
            const float4* pa = reinterpret_cast<const float4*>(gA + kn * 32);
            const float4* pb = reinterpret_cast<const float4*>(gB + kn * 32);
            a0 = pa[0]; a1 = pa[1]; a2 = pa[2]; a3 = pa[3];
            b0 = pb[0]; b1 = pb[1]; b2 = pb[2]; b3 = pb[3];
        }

        bf16x8 aF[4], bF[4];
#pragma unroll
        for (int i = 0; i < 4; i++)
            aF[i] = *reinterpret_cast<const bf16x8*>(rA[i]);
#pragma unroll
        for (int j = 0; j < 4; j++)
            bF[j] = *reinterpret_cast<const bf16x8*>(rB[j]);
#pragma unroll
        for (int i = 0; i < 4; i++)
#pragma unroll
            for (int j = 0; j < 4; j++)
                acc[i][j] = __builtin_amdgcn_mfma_f32_16x16x32_bf16(aF[i], bF[j], acc[i][j], 0, 0, 0);

        // advance LDS source pointers (kt indexes through rA/rB contents only)
        // (read pointers are fixed; staging pointers are fixed; only gA/gB
        //  offsets move, folded into the prefetch above)
    }

    // epilogue: store bf16 z; fused s_node = sum_d z*a_src (wave cols = one head)
    float av[4];
#pragma unroll
    for (int j = 0; j < 4; j++) av[j] = a_attn[j * 16 + l16];
    const int head = tileN * 2 + wn;
    const int colb = tileN * 128 + wn * 64;
#pragma unroll
    for (int i = 0; i < 4; i++) {
        const int rowb = tileM * 128 + wm * 64 + i * 16 + quad * 4;
#pragma unroll
        for (int r = 0; r < 4; r++) {
            const int row = rowb + r;
            const bool ok = row < N_TOKENS;
            float p = 0.0f;
#pragma unroll
            for (int j = 0; j < 4; j++) {
                const float v = acc[i][j][r];
                p += v * av[j];
                if (ok) z[(size_t)row * ZDIM + colb + j * 16 + l16] = f2bf(v);
            }
            p += __shfl_xor(p, 1);
            p += __shfl_xor(p, 2);
            p += __shfl_xor(p, 4);
            p += __shfl_xor(p, 8);
            if (ok && l16 == 0) s_node[row * HEADS + head] = p;
        }
    }
}

// ---------------------------------------------------------------------------
// CSR build (bounds-guarded)
// ---------------------------------------------------------------------------
__global__ void zero_kernel(int* __restrict__ p, int n) {
    int i = blockIdx.x * blockDim.x + threadIdx.x;
    if (i < n) p[i] = 0;
}

__global__ void hist_kernel(const int* __restrict__ edst, int* __restrict__ counts) {
    int i = blockIdx.x * blockDim.x + threadIdx.x;
    if (i < N_EDGES) {
        int d = edst[i];
        if ((unsigned)d < (unsigned)N_ARGS) atomicAdd(&counts[d], 1);
    }
}

__global__ void scan_kernel(const int* __restrict__ counts, int* __restrict__ offsets,
                            int* __restrict__ cursor) {
    __shared__ int partial[1024];
    const int tid = threadIdx.x;
    const int C = 20;  // 1024*20 >= 20000
    const int base = tid * C;
    int s = 0;
    for (int k = 0; k < C; k++) { int idx = base + k; if (idx < N_ARGS) s += counts[idx]; }
    partial[tid] = s;
    __syncthreads();
    for (int off = 1; off < 1024; off <<= 1) {
        int v = (tid >= off) ? partial[tid - off] : 0;
        __syncthreads();
        partial[tid] += v;
        __syncthreads();
    }
    int run = (tid == 0) ? 0 : partial[tid - 1];
    for (int k = 0; k < C; k++) {
        int idx = base + k;
        if (idx < N_ARGS) { offsets[idx] = run; cursor[idx] = run; run += counts[idx]; }
    }
    if (tid == 1023) offsets[N_ARGS] = run;
}

__global__ void scatter_kernel(const int* __restrict__ esrc, const int* __restrict__ edst,
                               int* __restrict__ cursor, int* __restrict__ ssrc) {
    int i = blockIdx.x * blockDim.x + threadIdx.x;
    if (i < N_EDGES) {
        int d = edst[i];
        if ((unsigned)d >= (unsigned)N_ARGS) return;
        int s = esrc[i];
        if ((unsigned)s >= (unsigned)N_TOKENS) s = 0;
        int pos = atomicAdd(&cursor[d], 1);
        ssrc[pos] = s;
    }
}

// ---------------------------------------------------------------------------
// Fused per-dst softmax + aggregation: one block per dst arg. OUT IS FP32.
// ---------------------------------------------------------------------------
__global__ __launch_bounds__(256) void agg_kernel(
    const int* __restrict__ offsets, const int* __restrict__ sorted_src,
    const float* __restrict__ s_node, const u16* __restrict__ z,
    float* __restrict__ out)
{
    const int dst = blockIdx.x;
    const int tid = threadIdx.x;
    const int wave = tid >> 6, lane = tid & 63;
    const int start = offsets[dst];
    const int nE = offsets[dst + 1] - start;
    if (nE <= 0) {
        out[(size_t)dst * ZDIM + tid] = 0.0f;
        out[(size_t)dst * ZDIM + tid + 256] = 0.0f;
        return;
    }
    __shared__ float m8[8];
    __shared__ float inv8[8];
    __shared__ float scratch[32];
    __shared__ int   src_lds[64];
    __shared__ float alpha_lds[64 * 8];

    // phase 1: per-head max of leaky_relu(s_node[src])
    float lm[8];
#pragma unroll
    for (int h = 0; h < 8; h++) lm[h] = -1e30f;
    for (int j = tid; j < nE; j += 256) {
        int s = sorted_src[start + j];
        if ((unsigned)s >= (unsigned)N_TOKENS) s = 0;
#pragma unroll
        for (int h = 0; h < 8; h++) {
            float v = s_node[s * 8 + h];
            v = v > 0.0f ? v : 0.01f * v;
            lm[h] = fmaxf(lm[h], v);
        }
    }
#pragma unroll
    for (int off = 1; off < 64; off <<= 1)
#pragma unroll
        for (int h = 0; h < 8; h++) lm[h] = fmaxf(lm[h], __shfl_xor(lm[h], off));
    if (lane == 0) {
#pragma unroll
        for (int h = 0; h < 8; h++) scratch[wave * 8 + h] = lm[h];
    }
    __syncthreads();
    if (tid < 8) {
        float r = scratch[tid];
        for (int w = 1; w < 4; w++) r = fmaxf(r, scratch[w * 8 + tid]);
        m8[tid] = r;
    }
    __syncthreads();

    // phase 2: denom
    float ls[8];
#pragma unroll
    for (int h = 0; h < 8; h++) ls[h] = 0.0f;
    for (int j = tid; j < nE; j += 256) {
        int s = sorted_src[start + j];
        if ((unsigned)s >= (unsigned)N_TOKENS) s = 0;
#pragma unroll
        for (int h = 0; h < 8; h++) {
            float v = s_node[s * 8 + h];
            v = v > 0.0f ? v : 0.01f * v;
            ls[h] += __expf(v - m8[h]);
        }
    }
#pragma unroll
    for (int off = 1; off < 64; off <<= 1)
#pragma unroll
        for (int h = 0; h < 8; h++) ls[h] += __shfl_xor(ls[h], off);
    if (lane == 0) {
#pragma unroll
        for (int h = 0; h < 8; h++) scratch[wave * 8 + h] = ls[h];
    }
    __syncthreads();
    if (tid < 8) {
        float d = scratch[tid];
        for (int w = 1; w < 4; w++) d += scratch[w * 8 + tid];
        if (d == 0.0f) d = 1.0f;
        inv8[tid] = 1.0f / d;
    }
    __syncthreads();

    // phase 3: out[dst] = sum alpha * z[src]; thread owns elems tid and tid+256
    float acc0 = 0.0f, acc1 = 0.0f;
    const int h1 = tid >> 6;
    for (int c0 = 0; c0 < nE; c0 += 64) {
        const int cn = min(64, nE - c0);
        for (int j = tid; j < cn; j += 256) {
            int s = sorted_src[start + c0 + j];
            if ((unsigned)s >= (unsigned)N_TOKENS) s = 0;
            src_lds[j] = s;
        }
        __syncthreads();
        for (int idx = tid; idx < cn * 8; idx += 256) {
            const int j = idx >> 3, h = idx & 7;
            float v = s_node[src_lds[j] * 8 + h];
            v = v > 0.0f ? v : 0.01f * v;
            alpha_lds[idx] = __expf(v - m8[h]) * inv8[h];
        }
        __syncthreads();
        for (int j = 0; j < cn; j++) {
            const int row = src_lds[j];
            acc0 += alpha_lds[j * 8 + h1]     * bf2f(z[(size_t)row * ZDIM + tid]);
            acc1 += alpha_lds[j * 8 + h1 + 4] * bf2f(z[(size_t)row * ZDIM + 256 + tid]);
        }
        __syncthreads();
    }
    out[(size_t)dst * ZDIM + tid] = acc0;
    out[(size_t)dst * ZDIM + 256 + tid] = acc1;
}

// ---------------------------------------------------------------------------
extern "C" void kernel_launch(void* const* d_in, const int* in_sizes, int n_in,
                              void* d_out, int out_size, void* d_ws, size_t ws_size,
                              hipStream_t stream) {
    const float* h      = (const float*)d_in[0];   // fp32 per reference
    const float* W      = (const float*)d_in[1];   // fp32
    const float* a_attn = (const float*)d_in[2];   // fp32
    const int* esrc     = (const int*)d_in[3];
    const int* edst     = (const int*)d_in[4];
    float* out          = (float*)d_out;           // fp32 output (reference dtype)

    char* ws = (char*)d_ws;
    u16*   z        = (u16*)ws;                         // 102,400,000 B
    float* s_node   = (float*)(ws + 102400000);         //   3,200,000 B
    int*   counts   = (int*)(ws + 105600000);           //      80,000 B
    int*   offsets  = (int*)(ws + 105680000);           //      80,016 B
    int*   cursor   = (int*)(ws + 105760016);           //      80,000 B
    int*   ssrc     = (int*)(ws + 105840016);           //   1,280,000 B -> 107.1 MB

    zero_kernel<<<(N_ARGS + 255) / 256, 256, 0, stream>>>(counts, N_ARGS);
    gemm_kernel<<<782 * 4, 256, 0, stream>>>(h, W, a_attn, z, s_node);
    hist_kernel<<<(N_EDGES + 255) / 256, 256, 0, stream>>>(edst, counts);
    scan_kernel<<<1, 1024, 0, stream>>>(counts, offsets, cursor);
    scatter_kernel<<<(N_EDGES + 255) / 256, 256, 0, stream>>>(esrc, edst, cursor, ssrc);
    agg_kernel<<<N_ARGS, 256, 0, stream>>>(offsets, ssrc, s_node, z, out);
}

// Round 2
// 717.718 us; speedup vs baseline: 1.0988x; 1.0988x over previous
//
#include <hip/hip_runtime.h>
#include <hip/hip_bf16.h>
#include <stdint.h>

#define N_TOKENS 100000
#define N_ARGS   20000
#define N_EDGES  320000
#define IN_DIM   768
#define HEADS    8
#define OUT_DIM  64
#define ZDIM     512   // HEADS*OUT_DIM

typedef unsigned short u16;
typedef unsigned int   u32;
typedef __bf16 bf16x8 __attribute__((ext_vector_type(8)));
typedef float  f32x4  __attribute__((ext_vector_type(4)));

__device__ __forceinline__ u16 f2bf(float f) {
    union { float f; u32 i; } v; v.f = f;
    u32 u = v.i;
    u += 0x7fffu + ((u >> 16) & 1u);   // RNE
    return (u16)(u >> 16);
}
__device__ __forceinline__ float bf2f(u16 u) {
    union { u32 i; float f; } v; v.i = ((u32)u) << 16; return v.f;
}
__device__ __forceinline__ u32 pk(float lo, float hi) {
    __hip_bfloat162 r = __float22bfloat162_rn(float2{lo, hi});
    union { __hip_bfloat162 b; u32 u; } v; v.b = r; return v.u;
}
__device__ __forceinline__ uint4 pack8(const float4 p, const float4 q) {
    uint4 w;
    w.x = pk(p.x, p.y); w.y = pk(p.z, p.w);
    w.z = pk(q.x, q.y); w.w = pk(q.z, q.w);
    return w;
}
// async global->LDS DMA, 16B per lane; LDS dest = wave-uniform base + lane*16
__device__ __forceinline__ void load_lds16(const void* g, void* l) {
    __builtin_amdgcn_global_load_lds(
        (const __attribute__((address_space(1))) void*)g,
        (__attribute__((address_space(3))) void*)l, 16, 0, 0);
}

// ---------------------------------------------------------------------------
// W fp32 -> bf16 (one-time, 786 KB)
// ---------------------------------------------------------------------------
__global__ __launch_bounds__(256) void convert_w(const float* __restrict__ W,
                                                 u16* __restrict__ Wbf) {
    const int i = blockIdx.x * blockDim.x + threadIdx.x;   // 8-elem chunk idx
    if (i < ZDIM * IN_DIM / 8) {
        const float4* p = reinterpret_cast<const float4*>(W + (size_t)i * 8);
        const float4 x = p[0], y = p[1];
        reinterpret_cast<uint4*>(Wbf)[i] = pack8(x, y);
    }
}

// ---------------------------------------------------------------------------
// GEMM: z[M,512] = h[M,768] @ W[512,768]^T
// Round-2: m97-structure DMA staging. A staged as fp32 via global_load_lds
// (16 KB tile), B staged as bf16 (8 KB) from pre-converted Wbf. LDS dest is
// linear; the swizzle lives in the per-lane GLOBAL source address (rule 21):
//   A: slot s of row r holds 16B chunk s ^ (r & 7)      (8 slots / 128B row)
//   B: slot s of row r holds 16B chunk s ^ ((r>>1) & 3) (4 slots /  64B row)
// Fragment reads use the matching XOR; A fragments convert f32->bf16 in-reg
// (cvt on the read path overlaps across waves; the store path is pure DMA).
// ---------------------------------------------------------------------------
__global__ __launch_bounds__(256) void gemm_kernel(
    const float* __restrict__ A,      // h [M, K] fp32
    const u16*   __restrict__ Bbf,    // W [512, K] bf16
    const float* __restrict__ a_attn, // [128] fp32, use first 64
    u16* __restrict__ z,              // [M, 512] bf16
    float* __restrict__ s_node)       // [M, 8] fp32
{
    __shared__ float As[128 * 32];    // 16 KB
    __shared__ u16   Bs[128 * 32];    //  8 KB

    const int tid  = threadIdx.x;
    const int wave = tid >> 6, lane = tid & 63;
    const int quad = lane >> 4, l16 = lane & 15;
    const int wm = wave >> 1, wn = wave & 1;

    // XCD-aware bijective swizzle: grid 3128 = 8 XCDs * 391 blocks.
    const int bx = blockIdx.x;
    const int lb = (bx & 7) * 391 + (bx >> 3);
    const int tileN = lb & 3;
    const int tileM = lb >> 2;

    // ---- DMA plumbing: A = 1024 slots (16 segs of 1 KB), B = 512 (8 segs)
    const char* srcA[4];
    void*       dstA[4];
#pragma unroll
    for (int g = 0; g < 4; g++) {
        const int idx = (wave * 4 + g) * 64 + lane;    // 16B slot index in As
        const int row = idx >> 3, s = idx & 7;
        const int c = s ^ (row & 7);                   // source 16B chunk
        int grow = tileM * 128 + row;
        if (grow >= N_TOKENS) grow = N_TOKENS - 1;
        srcA[g] = (const char*)(A + (size_t)grow * IN_DIM + c * 4);
        dstA[g] = (char*)As + (size_t)(wave * 4 + g) * 1024;
    }
    const char* srcB[2];
    void*       dstB[2];
#pragma unroll
    for (int g = 0; g < 2; g++) {
        const int idx = (wave * 2 + g) * 64 + lane;    // 16B slot index in Bs
        const int row = idx >> 2, s = idx & 3;
        const int c = s ^ ((row >> 1) & 3);
        srcB[g] = (const char*)(Bbf + (size_t)(tileN * 128 + row) * IN_DIM + c * 8);
        dstB[g] = (char*)Bs + (size_t)(wave * 2 + g) * 1024;
    }

    // ---- LDS read pointers (swizzled fragment layout)
    const float* rA0[4];
    const float* rA1[4];
    const u16*   rB[4];
#pragma unroll
    for (int i = 0; i < 4; i++) {
        int r = wm * 64 + i * 16 + l16;
        const int sl = (quad * 2) ^ (r & 7);
        rA0[i] = As + r * 32 + sl * 4;          // k = quad*8 .. +3
        rA1[i] = As + r * 32 + (sl ^ 1) * 4;    // k = quad*8+4 .. +7
        r = wn * 64 + i * 16 + l16;
        rB[i] = Bs + r * 32 + ((quad ^ ((r >> 1) & 3)) * 8);
    }

    f32x4 acc[4][4];
    const f32x4 zero4 = {0.f, 0.f, 0.f, 0.f};
#pragma unroll
    for (int i = 0; i < 4; i++)
#pragma unroll
        for (int j = 0; j < 4; j++) acc[i][j] = zero4;

    for (int kt = 0; kt < IN_DIM / 32; ++kt) {
        __syncthreads();   // previous iteration's LDS reads complete
#pragma unroll
        for (int g = 0; g < 4; g++) load_lds16(srcA[g], dstA[g]);
#pragma unroll
        for (int g = 0; g < 2; g++) load_lds16(srcB[g], dstB[g]);
        __syncthreads();   // compiler drains vmcnt(0) -> staged data visible

        bf16x8 aF[4], bF[4];
#pragma unroll
        for (int i = 0; i < 4; i++) {
            const float4 lo = *reinterpret_cast<const float4*>(rA0[i]);
            const float4 hi = *reinterpret_cast<const float4*>(rA1[i]);
            union { uint4 u; bf16x8 b; } cv;
            cv.u = pack8(lo, hi);
            aF[i] = cv.b;
        }
#pragma unroll
        for (int j = 0; j < 4; j++)
            bF[j] = *reinterpret_cast<const bf16x8*>(rB[j]);
#pragma unroll
        for (int i = 0; i < 4; i++)
#pragma unroll
            for (int j = 0; j < 4; j++)
                acc[i][j] = __builtin_amdgcn_mfma_f32_16x16x32_bf16(aF[i], bF[j], acc[i][j], 0, 0, 0);

#pragma unroll
        for (int g = 0; g < 4; g++) srcA[g] += 128;   // +32 f32
#pragma unroll
        for (int g = 0; g < 2; g++) srcB[g] += 64;    // +32 bf16
    }

    // epilogue: store bf16 z; fused s_node = sum_d z*a_src (wave cols = one head)
    float av[4];
#pragma unroll
    for (int j = 0; j < 4; j++) av[j] = a_attn[j * 16 + l16];
    const int head = tileN * 2 + wn;
    const int colb = tileN * 128 + wn * 64;
#pragma unroll
    for (int i = 0; i < 4; i++) {
        const int rowb = tileM * 128 + wm * 64 + i * 16 + quad * 4;
#pragma unroll
        for (int r = 0; r < 4; r++) {
            const int row = rowb + r;
            const bool ok = row < N_TOKENS;
            float p = 0.0f;
#pragma unroll
            for (int j = 0; j < 4; j++) {
                const float v = acc[i][j][r];
                p += v * av[j];
                if (ok) z[(size_t)row * ZDIM + colb + j * 16 + l16] = f2bf(v);
            }
            p += __shfl_xor(p, 1);
            p += __shfl_xor(p, 2);
            p += __shfl_xor(p, 4);
            p += __shfl_xor(p, 8);
            if (ok && l16 == 0) s_node[row * HEADS + head] = p;
        }
    }
}

// ---------------------------------------------------------------------------
// CSR build (bounds-guarded)
// ---------------------------------------------------------------------------
__global__ void zero_kernel(int* __restrict__ p, int n) {
    int i = blockIdx.x * blockDim.x + threadIdx.x;
    if (i < n) p[i] = 0;
}

__global__ void hist_kernel(const int* __restrict__ edst, int* __restrict__ counts) {
    int i = blockIdx.x * blockDim.x + threadIdx.x;
    if (i < N_EDGES) {
        int d = edst[i];
        if ((unsigned)d < (unsigned)N_ARGS) atomicAdd(&counts[d], 1);
    }
}

__global__ void scan_kernel(const int* __restrict__ counts, int* __restrict__ offsets,
                            int* __restrict__ cursor) {
    __shared__ int partial[1024];
    const int tid = threadIdx.x;
    const int C = 20;  // 1024*20 >= 20000
    const int base = tid * C;
    int s = 0;
    for (int k = 0; k < C; k++) { int idx = base + k; if (idx < N_ARGS) s += counts[idx]; }
    partial[tid] = s;
    __syncthreads();
    for (int off = 1; off < 1024; off <<= 1) {
        int v = (tid >= off) ? partial[tid - off] : 0;
        __syncthreads();
        partial[tid] += v;
        __syncthreads();
    }
    int run = (tid == 0) ? 0 : partial[tid - 1];
    for (int k = 0; k < C; k++) {
        int idx = base + k;
        if (idx < N_ARGS) { offsets[idx] = run; cursor[idx] = run; run += counts[idx]; }
    }
    if (tid == 1023) offsets[N_ARGS] = run;
}

__global__ void scatter_kernel(const int* __restrict__ esrc, const int* __restrict__ edst,
                               int* __restrict__ cursor, int* __restrict__ ssrc) {
    int i = blockIdx.x * blockDim.x + threadIdx.x;
    if (i < N_EDGES) {
        int d = edst[i];
        if ((unsigned)d >= (unsigned)N_ARGS) return;
        int s = esrc[i];
        if ((unsigned)s >= (unsigned)N_TOKENS) s = 0;
        int pos = atomicAdd(&cursor[d], 1);
        ssrc[pos] = s;
    }
}

// ---------------------------------------------------------------------------
// Fused per-dst softmax + aggregation: one block per dst arg. OUT IS FP32.
// ---------------------------------------------------------------------------
__global__ __launch_bounds__(256) void agg_kernel(
    const int* __restrict__ offsets, const int* __restrict__ sorted_src,
    const float* __restrict__ s_node, const u16* __restrict__ z,
    float* __restrict__ out)
{
    const int dst = blockIdx.x;
    const int tid = threadIdx.x;
    const int wave = tid >> 6, lane = tid & 63;
    const int start = offsets[dst];
    const int nE = offsets[dst + 1] - start;
    if (nE <= 0) {
        out[(size_t)dst * ZDIM + tid] = 0.0f;
        out[(size_t)dst * ZDIM + tid + 256] = 0.0f;
        return;
    }
    __shared__ float m8[8];
    __shared__ float inv8[8];
    __shared__ float scratch[32];
    __shared__ int   src_lds[64];
    __shared__ float alpha_lds[64 * 8];

    // phase 1: per-head max of leaky_relu(s_node[src])
    float lm[8];
#pragma unroll
    for (int h = 0; h < 8; h++) lm[h] = -1e30f;
    for (int j = tid; j < nE; j += 256) {
        int s = sorted_src[start + j];
        if ((unsigned)s >= (unsigned)N_TOKENS) s = 0;
#pragma unroll
        for (int h = 0; h < 8; h++) {
            float v = s_node[s * 8 + h];
            v = v > 0.0f ? v : 0.01f * v;
            lm[h] = fmaxf(lm[h], v);
        }
    }
#pragma unroll
    for (int off = 1; off < 64; off <<= 1)
#pragma unroll
        for (int h = 0; h < 8; h++) lm[h] = fmaxf(lm[h], __shfl_xor(lm[h], off));
    if (lane == 0) {
#pragma unroll
        for (int h = 0; h < 8; h++) scratch[wave * 8 + h] = lm[h];
    }
    __syncthreads();
    if (tid < 8) {
        float r = scratch[tid];
        for (int w = 1; w < 4; w++) r = fmaxf(r, scratch[w * 8 + tid]);
        m8[tid] = r;
    }
    __syncthreads();

    // phase 2: denom
    float ls[8];
#pragma unroll
    for (int h = 0; h < 8; h++) ls[h] = 0.0f;
    for (int j = tid; j < nE; j += 256) {
        int s = sorted_src[start + j];
        if ((unsigned)s >= (unsigned)N_TOKENS) s = 0;
#pragma unroll
        for (int h = 0; h < 8; h++) {
            float v = s_node[s * 8 + h];
            v = v > 0.0f ? v : 0.01f * v;
            ls[h] += __expf(v - m8[h]);
        }
    }
#pragma unroll
    for (int off = 1; off < 64; off <<= 1)
#pragma unroll
        for (int h = 0; h < 8; h++) ls[h] += __shfl_xor(ls[h], off);
    if (lane == 0) {
#pragma unroll
        for (int h = 0; h < 8; h++) scratch[wave * 8 + h] = ls[h];
    }
    __syncthreads();
    if (tid < 8) {
        float d = scratch[tid];
        for (int w = 1; w < 4; w++) d += scratch[w * 8 + tid];
        if (d == 0.0f) d = 1.0f;
        inv8[tid] = 1.0f / d;
    }
    __syncthreads();

    // phase 3: out[dst] = sum alpha * z[src]; thread owns elems tid and tid+256
    float acc0 = 0.0f, acc1 = 0.0f;
    const int h1 = tid >> 6;
    for (int c0 = 0; c0 < nE; c0 += 64) {
        const int cn = min(64, nE - c0);
        for (int j = tid; j < cn; j += 256) {
            int s = sorted_src[start + c0 + j];
            if ((unsigned)s >= (unsigned)N_TOKENS) s = 0;
            src_lds[j] = s;
        }
        __syncthreads();
        for (int idx = tid; idx < cn * 8; idx += 256) {
            const int j = idx >> 3, h = idx & 7;
            float v = s_node[src_lds[j] * 8 + h];
            v = v > 0.0f ? v : 0.01f * v;
            alpha_lds[idx] = __expf(v - m8[h]) * inv8[h];
        }
        __syncthreads();
        for (int j = 0; j < cn; j++) {
            const int row = src_lds[j];
            acc0 += alpha_lds[j * 8 + h1]     * bf2f(z[(size_t)row * ZDIM + tid]);
            acc1 += alpha_lds[j * 8 + h1 + 4] * bf2f(z[(size_t)row * ZDIM + 256 + tid]);
        }
        __syncthreads();
    }
    out[(size_t)dst * ZDIM + tid] = acc0;
    out[(size_t)dst * ZDIM + 256 + tid] = acc1;
}

// ---------------------------------------------------------------------------
extern "C" void kernel_launch(void* const* d_in, const int* in_sizes, int n_in,
                              void* d_out, int out_size, void* d_ws, size_t ws_size,
                              hipStream_t stream) {
    const float* h      = (const float*)d_in[0];   // fp32 per reference
    const float* W      = (const float*)d_in[1];   // fp32
    const float* a_attn = (const float*)d_in[2];   // fp32
    const int* esrc     = (const int*)d_in[3];
    const int* edst     = (const int*)d_in[4];
    float* out          = (float*)d_out;           // fp32 output (reference dtype)

    char* ws = (char*)d_ws;
    u16*   z        = (u16*)ws;                         // 102,400,000 B
    float* s_node   = (float*)(ws + 102400000);         //   3,200,000 B
    int*   counts   = (int*)(ws + 105600000);           //      80,000 B
    int*   offsets  = (int*)(ws + 105680000);           //      80,016 B
    int*   cursor   = (int*)(ws + 105760016);           //      80,000 B
    int*   ssrc     = (int*)(ws + 105840016);           //   1,280,000 B
    u16*   wbf      = (u16*)(ws + 107120016);           //     786,432 B -> 107.9 MB

    zero_kernel<<<(N_ARGS + 255) / 256, 256, 0, stream>>>(counts, N_ARGS);
    convert_w<<<(ZDIM * IN_DIM / 8 + 255) / 256, 256, 0, stream>>>(W, wbf);
    gemm_kernel<<<782 * 4, 256, 0, stream>>>(h, wbf, a_attn, z, s_node);
    hist_kernel<<<(N_EDGES + 255) / 256, 256, 0, stream>>>(edst, counts);
    scan_kernel<<<1, 1024, 0, stream>>>(counts, offsets, cursor);
    scatter_kernel<<<(N_EDGES + 255) / 256, 256, 0, stream>>>(esrc, edst, cursor, ssrc);
    agg_kernel<<<N_ARGS, 256, 0, stream>>>(offsets, ssrc, s_node, z, out);
}

// Round 3
// 711.884 us; speedup vs baseline: 1.1078x; 1.0082x over previous
//
#include <hip/hip_runtime.h>
#include <hip/hip_bf16.h>
#include <stdint.h>

#define N_TOKENS 100000
#define N_ARGS   20000
#define N_EDGES  320000
#define IN_DIM   768
#define HEADS    8
#define OUT_DIM  64
#define ZDIM     512   // HEADS*OUT_DIM

typedef unsigned short u16;
typedef unsigned int   u32;
typedef __bf16 bf16x8 __attribute__((ext_vector_type(8)));
typedef float  f32x4  __attribute__((ext_vector_type(4)));

__device__ __forceinline__ u16 f2bf(float f) {
    union { float f; u32 i; } v; v.f = f;
    u32 u = v.i;
    u += 0x7fffu + ((u >> 16) & 1u);   // RNE
    return (u16)(u >> 16);
}
__device__ __forceinline__ float bf2f(u16 u) {
    union { u32 i; float f; } v; v.i = ((u32)u) << 16; return v.f;
}
__device__ __forceinline__ u32 pk(float lo, float hi) {
    __hip_bfloat162 r = __float22bfloat162_rn(float2{lo, hi});
    union { __hip_bfloat162 b; u32 u; } v; v.b = r; return v.u;
}
__device__ __forceinline__ uint4 pack8(const float4 p, const float4 q) {
    uint4 w;
    w.x = pk(p.x, p.y); w.y = pk(p.z, p.w);
    w.z = pk(q.x, q.y); w.w = pk(q.z, q.w);
    return w;
}
// async global->LDS DMA, 16B per lane; LDS dest = wave-uniform base + lane*16
__device__ __forceinline__ void load_lds16(const void* g, void* l) {
    __builtin_amdgcn_global_load_lds(
        (const __attribute__((address_space(1))) void*)g,
        (__attribute__((address_space(3))) void*)l, 16, 0, 0);
}

// ---------------------------------------------------------------------------
// W fp32 -> bf16 (one-time, 786 KB)
// ---------------------------------------------------------------------------
__global__ __launch_bounds__(256) void convert_w(const float* __restrict__ W,
                                                 u16* __restrict__ Wbf) {
    const int i = blockIdx.x * blockDim.x + threadIdx.x;   // 8-elem chunk idx
    if (i < ZDIM * IN_DIM / 8) {
        const float4* p = reinterpret_cast<const float4*>(W + (size_t)i * 8);
        const float4 x = p[0], y = p[1];
        reinterpret_cast<uint4*>(Wbf)[i] = pack8(x, y);
    }
}

// ---------------------------------------------------------------------------
// GEMM: z[M,512] = h[M,768] @ W[512,768]^T
// Round-3: double-buffered DMA (T3 minimum 2-phase). Per K-step: issue next
// tile's global_load_lds into buf^1 FIRST, then ds_read + MFMA on buf, then
// one __syncthreads (its vmcnt(0) drain overlaps the whole compute phase
// instead of stalling cold-HBM latency serially). Source-address swizzle and
// read swizzle unchanged from verified round-2 kernel.
// ---------------------------------------------------------------------------
__global__ __launch_bounds__(256) void gemm_kernel(
    const float* __restrict__ A,      // h [M, K] fp32
    const u16*   __restrict__ Bbf,    // W [512, K] bf16
    const float* __restrict__ a_attn, // [128] fp32, use first 64
    u16* __restrict__ z,              // [M, 512] bf16
    float* __restrict__ s_node)       // [M, 8] fp32
{
    __shared__ float As[2][128 * 32];  // 32 KB (16 KB per buffer)
    __shared__ u16   Bs[2][128 * 32];  // 16 KB ( 8 KB per buffer)

    const int tid  = threadIdx.x;
    const int wave = tid >> 6, lane = tid & 63;
    const int quad = lane >> 4, l16 = lane & 15;
    const int wm = wave >> 1, wn = wave & 1;

    // XCD-aware bijective swizzle: grid 3128 = 8 XCDs * 391 blocks.
    const int bx = blockIdx.x;
    const int lb = (bx & 7) * 391 + (bx >> 3);
    const int tileN = lb & 3;
    const int tileM = lb >> 2;

    // ---- DMA plumbing: A = 1024 slots (16 segs of 1 KB), B = 512 (8 segs)
    const char* srcA[4];
    int         dA[4];
#pragma unroll
    for (int g = 0; g < 4; g++) {
        const int idx = (wave * 4 + g) * 64 + lane;    // 16B slot index in As
        const int row = idx >> 3, s = idx & 7;
        const int c = s ^ (row & 7);                   // source 16B chunk
        int grow = tileM * 128 + row;
        if (grow >= N_TOKENS) grow = N_TOKENS - 1;
        srcA[g] = (const char*)(A + (size_t)grow * IN_DIM + c * 4);
        dA[g] = (wave * 4 + g) * 1024;
    }
    const char* srcB[2];
    int         dB[2];
#pragma unroll
    for (int g = 0; g < 2; g++) {
        const int idx = (wave * 2 + g) * 64 + lane;    // 16B slot index in Bs
        const int row = idx >> 2, s = idx & 3;
        const int c = s ^ ((row >> 1) & 3);
        srcB[g] = (const char*)(Bbf + (size_t)(tileN * 128 + row) * IN_DIM + c * 8);
        dB[g] = (wave * 2 + g) * 1024;
    }

    // ---- LDS read pointers (swizzled fragment layout), relative to buffer 0
    const char* rA0[4];
    const char* rA1[4];
    const char* rB[4];
#pragma unroll
    for (int i = 0; i < 4; i++) {
        int r = wm * 64 + i * 16 + l16;
        const int sl = (quad * 2) ^ (r & 7);
        rA0[i] = (const char*)As + r * 128 + sl * 16;          // k = quad*8 .. +3
        rA1[i] = (const char*)As + r * 128 + (sl ^ 1) * 16;    // k = quad*8+4 .. +7
        r = wn * 64 + i * 16 + l16;
        rB[i] = (const char*)Bs + r * 64 + ((quad ^ ((r >> 1) & 3)) * 16);
    }

    f32x4 acc[4][4];
    const f32x4 zero4 = {0.f, 0.f, 0.f, 0.f};
#pragma unroll
    for (int i = 0; i < 4; i++)
#pragma unroll
        for (int j = 0; j < 4; j++) acc[i][j] = zero4;

    // prologue: stage tile 0 into buffer 0
#pragma unroll
    for (int g = 0; g < 4; g++) load_lds16(srcA[g], (char*)As + dA[g]);
#pragma unroll
    for (int g = 0; g < 2; g++) load_lds16(srcB[g], (char*)Bs + dB[g]);
    __syncthreads();   // drains vmcnt(0): tile 0 resident

    for (int kt = 0; kt < IN_DIM / 32; ++kt) {
        const int cur = kt & 1;
        const int nxt = cur ^ 1;

        // issue next tile's DMA first -> overlaps with this tile's compute
        if (kt < IN_DIM / 32 - 1) {
#pragma unroll
            for (int g = 0; g < 4; g++)
                load_lds16(srcA[g] + (size_t)(kt + 1) * 128,
                           (char*)As + nxt * 16384 + dA[g]);
#pragma unroll
            for (int g = 0; g < 2; g++)
                load_lds16(srcB[g] + (size_t)(kt + 1) * 64,
                           (char*)Bs + nxt * 8192 + dB[g]);
        }

        bf16x8 aF[4], bF[4];
#pragma unroll
        for (int i = 0; i < 4; i++) {
            const float4 lo = *reinterpret_cast<const float4*>(rA0[i] + cur * 16384);
            const float4 hi = *reinterpret_cast<const float4*>(rA1[i] + cur * 16384);
            union { uint4 u; bf16x8 b; } cv;
            cv.u = pack8(lo, hi);
            aF[i] = cv.b;
        }
#pragma unroll
        for (int j = 0; j < 4; j++)
            bF[j] = *reinterpret_cast<const bf16x8*>(rB[j] + cur * 8192);
#pragma unroll
        for (int i = 0; i < 4; i++)
#pragma unroll
            for (int j = 0; j < 4; j++)
                acc[i][j] = __builtin_amdgcn_mfma_f32_16x16x32_bf16(aF[i], bF[j], acc[i][j], 0, 0, 0);

        __syncthreads();   // one drain per K-step: next tile ready, reads done
    }

    // epilogue: store bf16 z; fused s_node = sum_d z*a_src (wave cols = one head)
    float av[4];
#pragma unroll
    for (int j = 0; j < 4; j++) av[j] = a_attn[j * 16 + l16];
    const int head = tileN * 2 + wn;
    const int colb = tileN * 128 + wn * 64;
#pragma unroll
    for (int i = 0; i < 4; i++) {
        const int rowb = tileM * 128 + wm * 64 + i * 16 + quad * 4;
#pragma unroll
        for (int r = 0; r < 4; r++) {
            const int row = rowb + r;
            const bool ok = row < N_TOKENS;
            float p = 0.0f;
#pragma unroll
            for (int j = 0; j < 4; j++) {
                const float v = acc[i][j][r];
                p += v * av[j];
                if (ok) z[(size_t)row * ZDIM + colb + j * 16 + l16] = f2bf(v);
            }
            p += __shfl_xor(p, 1);
            p += __shfl_xor(p, 2);
            p += __shfl_xor(p, 4);
            p += __shfl_xor(p, 8);
            if (ok && l16 == 0) s_node[row * HEADS + head] = p;
        }
    }
}

// ---------------------------------------------------------------------------
// CSR build (bounds-guarded)
// ---------------------------------------------------------------------------
__global__ void zero_kernel(int* __restrict__ p, int n) {
    int i = blockIdx.x * blockDim.x + threadIdx.x;
    if (i < n) p[i] = 0;
}

__global__ void hist_kernel(const int* __restrict__ edst, int* __restrict__ counts) {
    int i = blockIdx.x * blockDim.x + threadIdx.x;
    if (i < N_EDGES) {
        int d = edst[i];
        if ((unsigned)d < (unsigned)N_ARGS) atomicAdd(&counts[d], 1);
    }
}

__global__ void scan_kernel(const int* __restrict__ counts, int* __restrict__ offsets,
                            int* __restrict__ cursor) {
    __shared__ int partial[1024];
    const int tid = threadIdx.x;
    const int C = 20;  // 1024*20 >= 20000
    const int base = tid * C;
    int s = 0;
    for (int k = 0; k < C; k++) { int idx = base + k; if (idx < N_ARGS) s += counts[idx]; }
    partial[tid] = s;
    __syncthreads();
    for (int off = 1; off < 1024; off <<= 1) {
        int v = (tid >= off) ? partial[tid - off] : 0;
        __syncthreads();
        partial[tid] += v;
        __syncthreads();
    }
    int run = (tid == 0) ? 0 : partial[tid - 1];
    for (int k = 0; k < C; k++) {
        int idx = base + k;
        if (idx < N_ARGS) { offsets[idx] = run; cursor[idx] = run; run += counts[idx]; }
    }
    if (tid == 1023) offsets[N_ARGS] = run;
}

__global__ void scatter_kernel(const int* __restrict__ esrc, const int* __restrict__ edst,
                               int* __restrict__ cursor, int* __restrict__ ssrc) {
    int i = blockIdx.x * blockDim.x + threadIdx.x;
    if (i < N_EDGES) {
        int d = edst[i];
        if ((unsigned)d >= (unsigned)N_ARGS) return;
        int s = esrc[i];
        if ((unsigned)s >= (unsigned)N_TOKENS) s = 0;
        int pos = atomicAdd(&cursor[d], 1);
        ssrc[pos] = s;
    }
}

// ---------------------------------------------------------------------------
// Round-3 agg: ONE WAVE per dst (4 dsts/block), barrier-free.
//  - lane-per-edge online softmax over chunks of 64 (final m,sum identical
//    to reference's global-max two-pass formula)
//  - alpha -> LDS, then gather: each z row (1 KB) read by ONE wave
//    instruction (dwordx4, 16B/lane); lane owns 8 output cols.
// ---------------------------------------------------------------------------
__global__ __launch_bounds__(256) void agg_kernel(
    const int* __restrict__ offsets, const int* __restrict__ sorted_src,
    const float* __restrict__ s_node, const u16* __restrict__ z,
    float* __restrict__ out)
{
    const int tid  = threadIdx.x;
    const int wave = tid >> 6, lane = tid & 63;
    const int dst  = blockIdx.x * 4 + wave;

    __shared__ int   src_s[4][64];
    __shared__ float alpha_s[4][512];

    if (dst >= N_ARGS) return;

    const int start = offsets[dst];
    const int nE = offsets[dst + 1] - start;
    float* op = out + (size_t)dst * ZDIM + lane * 8;
    if (nE <= 0) {
        const f32x4 zz = {0.f, 0.f, 0.f, 0.f};
        *reinterpret_cast<f32x4*>(op)     = zz;
        *reinterpret_cast<f32x4*>(op + 4) = zz;
        return;
    }
    int*   srcw = src_s[wave];
    float* alw  = alpha_s[wave];
    const int hsel = lane >> 3;   // head owning this lane's 8 cols

    // ---- pass A: online per-head max + denom (exact: final m is global max)
    float m[8], ssum[8];
#pragma unroll
    for (int h = 0; h < 8; h++) { m[h] = -1e30f; ssum[h] = 0.f; }

    for (int c0 = 0; c0 < nE; c0 += 64) {
        float v[8];
        const bool act = (c0 + lane) < nE;
        if (act) {
            int s = sorted_src[start + c0 + lane];
            if ((unsigned)s >= (unsigned)N_TOKENS) s = 0;
            const float4* p = reinterpret_cast<const float4*>(s_node + (size_t)s * 8);
            const float4 x = p[0], y = p[1];
            v[0]=x.x; v[1]=x.y; v[2]=x.z; v[3]=x.w;
            v[4]=y.x; v[5]=y.y; v[6]=y.z; v[7]=y.w;
#pragma unroll
            for (int h = 0; h < 8; h++) v[h] = v[h] > 0.f ? v[h] : 0.01f * v[h];
        } else {
#pragma unroll
            for (int h = 0; h < 8; h++) v[h] = -1e30f;
        }
        float cm[8];
#pragma unroll
        for (int h = 0; h < 8; h++) cm[h] = v[h];
#pragma unroll
        for (int off = 1; off < 64; off <<= 1)
#pragma unroll
            for (int h = 0; h < 8; h++) cm[h] = fmaxf(cm[h], __shfl_xor(cm[h], off));
        float ce[8];
#pragma unroll
        for (int h = 0; h < 8; h++) {
            const float mn = fmaxf(m[h], cm[h]);
            ce[h] = act ? __expf(v[h] - mn) : 0.f;
            ssum[h] *= __expf(m[h] - mn);
            m[h] = mn;
        }
#pragma unroll
        for (int off = 1; off < 64; off <<= 1)
#pragma unroll
            for (int h = 0; h < 8; h++) ce[h] += __shfl_xor(ce[h], off);
#pragma unroll
        for (int h = 0; h < 8; h++) ssum[h] += ce[h];
    }
    float inv[8];
#pragma unroll
    for (int h = 0; h < 8; h++) {
        float d = ssum[h]; if (d == 0.f) d = 1.f; inv[h] = 1.f / d;
    }

    // ---- pass B: alpha -> LDS, then per-edge weighted gather of z rows
    f32x4 acc0 = {0.f,0.f,0.f,0.f}, acc1 = {0.f,0.f,0.f,0.f};
    for (int c0 = 0; c0 < nE; c0 += 64) {
        const int cn = min(64, nE - c0);
        if (lane < cn) {
            int s = sorted_src[start + c0 + lane];
            if ((unsigned)s >= (unsigned)N_TOKENS) s = 0;
            srcw[lane] = s;
            const float4* p = reinterpret_cast<const float4*>(s_node + (size_t)s * 8);
            const float4 x = p[0], y = p[1];
            float v[8];
            v[0]=x.x; v[1]=x.y; v[2]=x.z; v[3]=x.w;
            v[4]=y.x; v[5]=y.y; v[6]=y.z; v[7]=y.w;
#pragma unroll
            for (int h = 0; h < 8; h++) {
                const float u = v[h] > 0.f ? v[h] : 0.01f * v[h];
                alw[lane * 8 + h] = __expf(u - m[h]) * inv[h];
            }
        }
        // wave-internal LDS visibility (no cross-wave sharing -> no barrier)
        asm volatile("s_waitcnt lgkmcnt(0)" ::: "memory");
        for (int j = 0; j < cn; ++j) {
            const int   row = srcw[j];
            const float a   = alw[j * 8 + hsel];
            const uint4 zr  = *reinterpret_cast<const uint4*>(
                                  z + (size_t)row * ZDIM + lane * 8);
            acc0.x += a * bf2f((u16)(zr.x & 0xffffu));
            acc0.y += a * bf2f((u16)(zr.x >> 16));
            acc0.z += a * bf2f((u16)(zr.y & 0xffffu));
            acc0.w += a * bf2f((u16)(zr.y >> 16));
            acc1.x += a * bf2f((u16)(zr.z & 0xffffu));
            acc1.y += a * bf2f((u16)(zr.z >> 16));
            acc1.z += a * bf2f((u16)(zr.w & 0xffffu));
            acc1.w += a * bf2f((u16)(zr.w >> 16));
        }
    }
    *reinterpret_cast<f32x4*>(op)     = acc0;
    *reinterpret_cast<f32x4*>(op + 4) = acc1;
}

// ---------------------------------------------------------------------------
extern "C" void kernel_launch(void* const* d_in, const int* in_sizes, int n_in,
                              void* d_out, int out_size, void* d_ws, size_t ws_size,
                              hipStream_t stream) {
    const float* h      = (const float*)d_in[0];   // fp32 per reference
    const float* W      = (const float*)d_in[1];   // fp32
    const float* a_attn = (const float*)d_in[2];   // fp32
    const int* esrc     = (const int*)d_in[3];
    const int* edst     = (const int*)d_in[4];
    float* out          = (float*)d_out;           // fp32 output (reference dtype)

    char* ws = (char*)d_ws;
    u16*   z        = (u16*)ws;                         // 102,400,000 B
    float* s_node   = (float*)(ws + 102400000);         //   3,200,000 B
    int*   counts   = (int*)(ws + 105600000);           //      80,000 B
    int*   offsets  = (int*)(ws + 105680000);           //      80,016 B
    int*   cursor   = (int*)(ws + 105760016);           //      80,000 B
    int*   ssrc     = (int*)(ws + 105840016);           //   1,280,000 B
    u16*   wbf      = (u16*)(ws + 107120016);           //     786,432 B -> 107.9 MB

    zero_kernel<<<(N_ARGS + 255) / 256, 256, 0, stream>>>(counts, N_ARGS);
    convert_w<<<(ZDIM * IN_DIM / 8 + 255) / 256, 256, 0, stream>>>(W, wbf);
    gemm_kernel<<<782 * 4, 256, 0, stream>>>(h, wbf, a_attn, z, s_node);
    hist_kernel<<<(N_EDGES + 255) / 256, 256, 0, stream>>>(edst, counts);
    scan_kernel<<<1, 1024, 0, stream>>>(counts, offsets, cursor);
    scatter_kernel<<<(N_EDGES + 255) / 256, 256, 0, stream>>>(esrc, edst, cursor, ssrc);
    agg_kernel<<<(N_ARGS + 3) / 4, 256, 0, stream>>>(offsets, ssrc, s_node, z, out);
}